// Round 8
// baseline (191.704 us; speedup 1.0000x reference)
//
#include <hip/hip_runtime.h>
#include <hip/hip_bf16.h>

#define NN   12800
#define TT   20
#define HID  128
#define SPB  16     // seqs per block

typedef __attribute__((ext_vector_type(8))) short          bf16x8;
typedef __attribute__((ext_vector_type(8))) unsigned short ushort8;
typedef __attribute__((ext_vector_type(4))) float          f32x4;

// projE[(d*512+v)*512 + u*4 + q] = bias[q*128+u] + sum_e Wih[q*128+u][e]*embed[v][e]
// (q = gate type 0..3 = i,f,g,o ; u = unit 0..127)
__device__ float g_projE[2 * 512 * 512];
// Whh packed as MFMA B-fragments (bf16 bits), 8-wave layout:
// [(((d*8+w)*4+nt)*4+kt)*64+lane][i] = Whh_d[nt*128 + w*16 + (lane&15)][kt*32 + (lane>>4)*8 + i]
__device__ __align__(16) unsigned short g_Bpk8[2 * 8 * 4 * 4 * 64 * 8];

__device__ __forceinline__ unsigned short f2bf(float f) {
    union { float f; unsigned u; } a; a.f = f;
    unsigned r = a.u + 0x7FFF + ((a.u >> 16) & 1);
    return (unsigned short)(r >> 16);
}
__device__ __forceinline__ float sigm(float v) {
    return __builtin_amdgcn_rcpf(1.0f + __expf(-v));
}
__device__ __forceinline__ float tanh_(float v) {
    return fmaf(2.0f, __builtin_amdgcn_rcpf(1.0f + __expf(-2.0f * v)), -1.0f);
}

// ---- prep 1: char -> gate-preact table (includes bias) ----
__global__ void prep_proj(const float* __restrict__ embed,
                          const float* __restrict__ Wih_f, const float* __restrict__ b_f,
                          const float* __restrict__ Wih_b, const float* __restrict__ b_b)
{
    const int v = blockIdx.x;   // char
    const int d = blockIdx.y;   // dir
    const int g = threadIdx.x;  // gate row 0..511
    __shared__ float ev[HID];
    if (g < HID) ev[g] = embed[v * HID + g];
    __syncthreads();
    const float* Wi = d ? Wih_b : Wih_f;
    const float* bb = d ? b_b   : b_f;
    float a = bb[g];
    #pragma unroll 8
    for (int e = 0; e < HID; ++e) a = fmaf(Wi[g * HID + e], ev[e], a);
    g_projE[(d * 512 + v) * 512 + (g & 127) * 4 + (g >> 7)] = a;
}

// ---- prep 2: pack Whh into 8-wave B fragments (bf16) ----
__global__ void prep_bpack8(const float* __restrict__ Whh_f, const float* __restrict__ Whh_b)
{
    const int id = blockIdx.x * 256 + threadIdx.x;   // 0..16383
    const int lane = id & 63;
    const int kt   = (id >> 6) & 3;
    const int nt   = (id >> 8) & 3;
    const int w    = (id >> 10) & 7;
    const int d    = id >> 13;
    const float* Wh = d ? Whh_b : Whh_f;
    const int row = nt * 128 + w * 16 + (lane & 15);
    const int k0  = kt * 32 + (lane >> 4) * 8;
    ushort8 o;
    #pragma unroll
    for (int i = 0; i < 8; ++i) o[i] = f2bf(Wh[row * HID + k0 + i]);
    reinterpret_cast<ushort8*>(g_Bpk8)[id] = o;
}

// one LSTM step; HC/HN = LDS h ping-pong, QC = this step's proj regs,
// QN = prefetch target for step tn. All names static.
#define STEP(tc, QC, QN, tn, HC, HN)                                          \
{                                                                             \
    bf16x8 A[4];                                                              \
    _Pragma("unroll")                                                         \
    for (int kt = 0; kt < 4; ++kt)                                            \
        A[kt] = *reinterpret_cast<const bf16x8*>(&HC[c0 * 136 + kt * 32 + rg * 8]); \
    f32x4 acc[4];                                                             \
    _Pragma("unroll")                                                         \
    for (int q = 0; q < 4; ++q) {                                             \
        _Pragma("unroll")                                                     \
        for (int r = 0; r < 4; ++r) acc[q][r] = QC[r][q];                     \
    }                                                                         \
    _Pragma("unroll")                                                         \
    for (int r = 0; r < 4; ++r) {                                             \
        const int ch = chars[(rg * 4 + r) * TT + (tn)];                       \
        QN[r] = *reinterpret_cast<const f32x4*>(                              \
            g_projE + (dir * 512 + ch) * 512 + u * 4);                        \
    }                                                                         \
    _Pragma("unroll")                                                         \
    for (int kt = 0; kt < 4; ++kt) {                                          \
        _Pragma("unroll")                                                     \
        for (int q = 0; q < 4; ++q)                                           \
            acc[q] = __builtin_amdgcn_mfma_f32_16x16x32_bf16(A[kt], B[q][kt], acc[q], 0, 0, 0); \
    }                                                                         \
    _Pragma("unroll")                                                         \
    for (int r = 0; r < 4; ++r) {                                             \
        const float iv = sigm(acc[0][r]);                                     \
        const float fv = sigm(acc[1][r]);                                     \
        const float gv = tanh_(acc[2][r]);                                    \
        const float ov = sigm(acc[3][r]);                                     \
        const float cn = fmaf(fv, cst[r], iv * gv);                           \
        const float hn = ov * tanh_(cn);                                      \
        const bool valid = ((tc) < len4[r]);                                  \
        cst[r]  = valid ? cn : cst[r];                                        \
        hreg[r] = valid ? hn : hreg[r];                                       \
        HN[(rg * 4 + r) * 136 + u] = f2bf(hreg[r]);                           \
    }                                                                         \
    __syncthreads();                                                          \
}

// ---- main: 16 seqs/block, 8 waves; wave w owns units w*16..w*16+15 (all 4 gates) ----
__global__ __launch_bounds__(512) void lstm_mfma8(
    const int* __restrict__ x, float* __restrict__ out)
{
    __shared__ __align__(16) unsigned short h0[SPB * 136];  // bf16 h ping
    __shared__ __align__(16) unsigned short h1[SPB * 136];  // bf16 h pong
    __shared__ int chars[SPB * TT];
    __shared__ int len_sh[SPB];

    const int tid  = threadIdx.x;
    const int lane = tid & 63;
    const int w    = tid >> 6;         // wave id 0..7
    const int c0   = lane & 15;
    const int rg   = lane >> 4;
    const int u    = w * 16 + c0;      // this lane's hidden unit
    const int dir  = blockIdx.y;
    const int n0   = blockIdx.x * SPB;

    if (tid < SPB * TT) chars[tid] = x[n0 * TT + tid];
    for (int i = tid; i < SPB * 136; i += 512) { h0[i] = 0; h1[i] = 0; }
    __syncthreads();
    if (tid < SPB) {
        int l = 0;
        #pragma unroll
        for (int t = 0; t < TT; ++t) l += (chars[tid * TT + t] > 0) ? 1 : 0;
        len_sh[tid] = l;
    }

    // resident B fragments: 4 gate-type tiles x 4 k-frags = 64 VGPRs, pinned
    bf16x8 B[4][4];
    {
        const bf16x8* Bp = reinterpret_cast<const bf16x8*>(g_Bpk8);
        #pragma unroll
        for (int nt = 0; nt < 4; ++nt)
            #pragma unroll
            for (int kt = 0; kt < 4; ++kt)
                B[nt][kt] = Bp[((((dir * 8 + w) * 4 + nt) * 4 + kt) * 64) + lane];
    }
    // pin: make rematerialization impossible (force true residency)
    asm volatile("" :
        "+v"(B[0][0]), "+v"(B[0][1]), "+v"(B[0][2]), "+v"(B[0][3]),
        "+v"(B[1][0]), "+v"(B[1][1]), "+v"(B[1][2]), "+v"(B[1][3]),
        "+v"(B[2][0]), "+v"(B[2][1]), "+v"(B[2][2]), "+v"(B[2][3]),
        "+v"(B[3][0]), "+v"(B[3][1]), "+v"(B[3][2]), "+v"(B[3][3]));
    __syncthreads();

    int len4[4];
    #pragma unroll
    for (int r = 0; r < 4; ++r) len4[r] = len_sh[rg * 4 + r];

    float cst[4]  = {};   // cell state per r
    float hreg[4] = {};   // fp32 h for final output

    // preload proj for step 0
    f32x4 qA[4], qB[4];
    {
        const int tfirst = dir ? (TT - 1) : 0;
        #pragma unroll
        for (int r = 0; r < 4; ++r) {
            const int ch = chars[(rg * 4 + r) * TT + tfirst];
            qA[r] = *reinterpret_cast<const f32x4*>(
                g_projE + (dir * 512 + ch) * 512 + u * 4);
        }
    }

    for (int step = 0; step < TT; step += 2) {
        const int t0 = dir ? (TT - 1 - step) : step;
        const int t1 = dir ? (TT - 2 - step) : (step + 1);
        const int t2 = (step + 2 < TT) ? (dir ? (TT - 3 - step) : (step + 2)) : 0;
        STEP(t0, qA, qB, t1, h0, h1)
        STEP(t1, qB, qA, t2, h1, h0)
    }

    #pragma unroll
    for (int r = 0; r < 4; ++r)
        out[(n0 + rg * 4 + r) * 256 + dir * 128 + u] = hreg[r];
}

extern "C" void kernel_launch(void* const* d_in, const int* in_sizes, int n_in,
                              void* d_out, int out_size, void* d_ws, size_t ws_size,
                              hipStream_t stream)
{
    const int*   x     = (const int*)  d_in[0];
    const float* embed = (const float*)d_in[1];
    const float* Wih_f = (const float*)d_in[2];
    const float* Whh_f = (const float*)d_in[3];
    const float* b_f   = (const float*)d_in[4];
    const float* Wih_b = (const float*)d_in[5];
    const float* Whh_b = (const float*)d_in[6];
    const float* b_b   = (const float*)d_in[7];
    float* out = (float*)d_out;

    prep_proj  <<<dim3(512, 2), 512, 0, stream>>>(embed, Wih_f, b_f, Wih_b, b_b);
    prep_bpack8<<<64, 256, 0, stream>>>(Whh_f, Whh_b);
    lstm_mfma8 <<<dim3(NN / SPB, 2), 512, 0, stream>>>(x, out);
}

// Round 9
// 130.341 us; speedup vs baseline: 1.4708x; 1.4708x over previous
//
#include <hip/hip_runtime.h>
#include <hip/hip_bf16.h>

#define NN   12800
#define TT   20
#define HID  128
#define SPB  16     // seqs per block

typedef __attribute__((ext_vector_type(8))) short          bf16x8;
typedef __attribute__((ext_vector_type(8))) unsigned short ushort8;
typedef __attribute__((ext_vector_type(4))) float          f32x4;

#define L2E 1.4426950408889634f
#define K2  2.8853900817779268f   // 2*log2(e)

// proj table (scaled by L2E / K2 per gate type), vector layout:
// g_projV[((d*512+v)*4 + w)*128 + c0*8 + nt], gate g=(nt*16+c0)*4+w
__device__ float g_projV[2 * 512 * 4 * 128];
// Whh B-fragments (bf16 bits, scaled), 4-wave layout with K-permutation sigma:
// [(((d*4+w)*8+nt)*4+kt)*64+lane][i] = sc*Whh_d[(nt*16+(lane&15))*4+w][sigma(kt,lane>>4,i)]
// sigma(kt,rg,i) = (i&1)*64 + (kt*4+rg)*4 + (i>>1)   (matches h-LDS unit permutation)
__device__ __align__(16) unsigned short g_Bpk[2 * 4 * 8 * 4 * 64 * 8];

__device__ __forceinline__ unsigned short f2bf(float f) {
    union { float f; unsigned u; } a; a.f = f;
    unsigned r = a.u + 0x7FFF + ((a.u >> 16) & 1);
    return (unsigned short)(r >> 16);
}
__device__ __forceinline__ float ex2(float x) {   // 2^x, raw v_exp_f32
#if __has_builtin(__builtin_amdgcn_exp2f)
    return __builtin_amdgcn_exp2f(x);
#else
    float r; asm("v_exp_f32 %0, %1" : "=v"(r) : "v"(x)); return r;
#endif
}

// ---- prep 1: char -> scaled gate-preact table; 4 chars per block ----
__global__ __launch_bounds__(512) void prep_proj(
    const float* __restrict__ embed,
    const float* __restrict__ Wih_f, const float* __restrict__ b_f,
    const float* __restrict__ Wih_b, const float* __restrict__ b_b)
{
    const int vg = blockIdx.x;   // group of 4 chars
    const int d  = blockIdx.y;
    const int g  = threadIdx.x;  // gate 0..511
    __shared__ __align__(16) float ev[4][HID];
    ev[g >> 7][g & 127] = embed[(vg * 4 + (g >> 7)) * HID + (g & 127)];
    __syncthreads();
    const float* Wi = d ? Wih_b : Wih_f;
    const float* bb = d ? b_b : b_f;
    const f32x4* Wrow = reinterpret_cast<const f32x4*>(Wi + g * HID);
    float acc[4] = {0.f, 0.f, 0.f, 0.f};
    #pragma unroll 8
    for (int k4 = 0; k4 < 32; ++k4) {
        const f32x4 wv = Wrow[k4];
        #pragma unroll
        for (int j = 0; j < 4; ++j) {
            acc[0] = fmaf(wv[j], ev[0][k4 * 4 + j], acc[0]);
            acc[1] = fmaf(wv[j], ev[1][k4 * 4 + j], acc[1]);
            acc[2] = fmaf(wv[j], ev[2][k4 * 4 + j], acc[2]);
            acc[3] = fmaf(wv[j], ev[3][k4 * 4 + j], acc[3]);
        }
    }
    const float sc = ((g >> 7) == 2) ? K2 : L2E;
    const float bv = bb[g];
    const int slot = (g & 3) * 128 + ((g >> 2) & 15) * 8 + (g >> 6);
    #pragma unroll
    for (int v = 0; v < 4; ++v)
        g_projV[(d * 512 + vg * 4 + v) * 512 + slot] = (bv + acc[v]) * sc;
}

// ---- prep 2: pack scaled Whh into B fragments with sigma K-permutation ----
__global__ void prep_bpack(const float* __restrict__ Whh_f, const float* __restrict__ Whh_b)
{
    const int id = blockIdx.x * 256 + threadIdx.x;   // 0..16383
    const int lane = id & 63;
    const int kt   = (id >> 6) & 3;
    const int nt   = (id >> 8) & 7;
    const int w    = (id >> 11) & 3;
    const int d    = id >> 13;
    const int rg   = lane >> 4;
    const float* Wh = d ? Whh_b : Whh_f;
    const int gB = (nt * 16 + (lane & 15)) * 4 + w;
    const float sc = ((gB >> 7) == 2) ? K2 : L2E;
    ushort8 o;
    #pragma unroll
    for (int i = 0; i < 8; ++i) {
        const int col = (i & 1) * 64 + (kt * 4 + rg) * 4 + (i >> 1);
        o[i] = f2bf(Wh[gB * HID + col] * sc);
    }
    reinterpret_cast<ushort8*>(g_Bpk)[id] = o;
}

// one LSTM step. h-LDS rows hold units in permuted order pos(u)=(u&63)*2+(u>>6),
// so (u,u+64) pack into one b32 write; A-reads stay linear (sigma baked into B).
#define STEP(tc, QC, QN, tn, HC, HN)                                          \
{                                                                             \
    bf16x8 A[4];                                                              \
    _Pragma("unroll")                                                         \
    for (int kt = 0; kt < 4; ++kt)                                            \
        A[kt] = *reinterpret_cast<const bf16x8*>(&HC[c0 * 136 + kt * 32 + rg * 8]); \
    f32x4 acc[8];                                                             \
    _Pragma("unroll")                                                         \
    for (int r = 0; r < 4; ++r) {                                             \
        _Pragma("unroll")                                                     \
        for (int j = 0; j < 4; ++j) {                                         \
            acc[j][r]     = QC[r][0][j];                                      \
            acc[4 + j][r] = QC[r][1][j];                                      \
        }                                                                     \
    }                                                                         \
    _Pragma("unroll")                                                         \
    for (int r = 0; r < 4; ++r) {                                             \
        const int ch = chars[(rg * 4 + r) * TT + (tn)];                       \
        const f32x4* p = reinterpret_cast<const f32x4*>(                      \
            g_projV + ((dir * 512 + ch) * 4 + w) * 128 + c0 * 8);             \
        QN[r][0] = p[0];                                                      \
        QN[r][1] = p[1];                                                      \
    }                                                                         \
    _Pragma("unroll")                                                         \
    for (int kt = 0; kt < 4; ++kt) {                                          \
        _Pragma("unroll")                                                     \
        for (int nt = 0; nt < 8; ++nt)                                        \
            acc[nt] = __builtin_amdgcn_mfma_f32_16x16x32_bf16(A[kt], B[nt][kt], acc[nt], 0, 0, 0); \
    }                                                                         \
    _Pragma("unroll")                                                         \
    for (int r = 0; r < 4; ++r) {                                             \
        const bool valid = ((tc) < len4[r]);                                  \
        float hh0, hh1;                                                       \
        {                                                                     \
            const float ei = ex2(-acc[0][r]);                                 \
            const float ef = ex2(-acc[2][r]);                                 \
            const float tg = ex2(-acc[4][r]);                                 \
            const float eo = ex2(-acc[6][r]);                                 \
            const float rf = __builtin_amdgcn_rcpf(1.0f + ef);                \
            const float rr = __builtin_amdgcn_rcpf((1.0f + ei) * (1.0f + tg));\
            const float cn = fmaf(rf, cst[0][r], fmaf(-K2, tg, K2) * rr);     \
            const float ec = ex2(-cn);                                        \
            const float r2 = __builtin_amdgcn_rcpf((1.0f + eo) * (1.0f + ec));\
            const float hn = (1.0f - ec) * r2;                                \
            cst[0][r]  = valid ? cn : cst[0][r];                              \
            hreg[0][r] = valid ? hn : hreg[0][r];                             \
            hh0 = hreg[0][r];                                                 \
        }                                                                     \
        {                                                                     \
            const float ei = ex2(-acc[1][r]);                                 \
            const float ef = ex2(-acc[3][r]);                                 \
            const float tg = ex2(-acc[5][r]);                                 \
            const float eo = ex2(-acc[7][r]);                                 \
            const float rf = __builtin_amdgcn_rcpf(1.0f + ef);                \
            const float rr = __builtin_amdgcn_rcpf((1.0f + ei) * (1.0f + tg));\
            const float cn = fmaf(rf, cst[1][r], fmaf(-K2, tg, K2) * rr);     \
            const float ec = ex2(-cn);                                        \
            const float r2 = __builtin_amdgcn_rcpf((1.0f + eo) * (1.0f + ec));\
            const float hn = (1.0f - ec) * r2;                                \
            cst[1][r]  = valid ? cn : cst[1][r];                              \
            hreg[1][r] = valid ? hn : hreg[1][r];                             \
            hh1 = hreg[1][r];                                                 \
        }                                                                     \
        unsigned hw;                                                          \
        asm("v_cvt_pk_bf16_f32 %0, %1, %2" : "=v"(hw) : "v"(hh0), "v"(hh1));  \
        *reinterpret_cast<unsigned*>(&HN[(rg * 4 + r) * 136 + (c0 * 4 + w) * 2]) = hw; \
    }                                                                         \
    __syncthreads();                                                          \
}

// ---- main: 16 seqs/block, 4 waves; wave w owns gates g==w (mod 4) ----
__global__ __launch_bounds__(256, 2) void lstm_mfma(
    const int* __restrict__ x, float* __restrict__ out)
{
    __shared__ __align__(16) unsigned short h0[SPB * 136];  // bf16 h ping (permuted units)
    __shared__ __align__(16) unsigned short h1[SPB * 136];  // bf16 h pong
    __shared__ int chars[SPB * TT];
    __shared__ int len_sh[SPB];

    const int tid  = threadIdx.x;
    const int lane = tid & 63;
    const int w    = tid >> 6;         // wave id 0..3
    const int c0   = lane & 15;        // A row (=seq within quad-group) / D col
    const int rg   = lane >> 4;
    const int dir  = blockIdx.y;
    const int n0   = blockIdx.x * SPB;

    for (int i = tid; i < SPB * TT; i += 256) chars[i] = x[n0 * TT + i];
    for (int i = tid; i < SPB * 136; i += 256) { h0[i] = 0; h1[i] = 0; }
    __syncthreads();
    if (tid < SPB) {
        int l = 0;
        #pragma unroll
        for (int t = 0; t < TT; ++t) l += (chars[tid * TT + t] > 0) ? 1 : 0;
        len_sh[tid] = l;
    }

    // B fragments: 8 n-tiles x 4 k-frags (compiler may refetch from L2 - proven OK)
    bf16x8 B[8][4];
    {
        const bf16x8* Bp = reinterpret_cast<const bf16x8*>(g_Bpk);
        #pragma unroll
        for (int nt = 0; nt < 8; ++nt)
            #pragma unroll
            for (int kt = 0; kt < 4; ++kt)
                B[nt][kt] = Bp[((((dir * 4 + w) * 8 + nt) * 4 + kt) * 64) + lane];
    }
    __syncthreads();

    int len4[4];
    #pragma unroll
    for (int r = 0; r < 4; ++r) len4[r] = len_sh[rg * 4 + r];

    float cst[2][4]  = {};   // scaled cell state (K2*c)
    float hreg[2][4] = {};   // fp32 h for final output

    f32x4 qA[4][2], qB[4][2];
    {
        const int tfirst = dir ? (TT - 1) : 0;
        #pragma unroll
        for (int r = 0; r < 4; ++r) {
            const int ch = chars[(rg * 4 + r) * TT + tfirst];
            const f32x4* p = reinterpret_cast<const f32x4*>(
                g_projV + ((dir * 512 + ch) * 4 + w) * 128 + c0 * 8);
            qA[r][0] = p[0];
            qA[r][1] = p[1];
        }
    }

    for (int step = 0; step < TT; step += 2) {
        const int t0 = dir ? (TT - 1 - step) : step;
        const int t1 = dir ? (TT - 2 - step) : (step + 1);
        const int t2 = (step + 2 < TT) ? (dir ? (TT - 3 - step) : (step + 2)) : 0;
        STEP(t0, qA, qB, t1, h0, h1)
        STEP(t1, qB, qA, t2, h1, h0)
    }

    #pragma unroll
    for (int r = 0; r < 4; ++r) {
        out[(n0 + rg * 4 + r) * 256 + dir * 128 + c0 * 4 + w]      = hreg[0][r];
        out[(n0 + rg * 4 + r) * 256 + dir * 128 + 64 + c0 * 4 + w] = hreg[1][r];
    }
}

extern "C" void kernel_launch(void* const* d_in, const int* in_sizes, int n_in,
                              void* d_out, int out_size, void* d_ws, size_t ws_size,
                              hipStream_t stream)
{
    const int*   x     = (const int*)  d_in[0];
    const float* embed = (const float*)d_in[1];
    const float* Wih_f = (const float*)d_in[2];
    const float* Whh_f = (const float*)d_in[3];
    const float* b_f   = (const float*)d_in[4];
    const float* Wih_b = (const float*)d_in[5];
    const float* Whh_b = (const float*)d_in[6];
    const float* b_b   = (const float*)d_in[7];
    float* out = (float*)d_out;

    prep_proj <<<dim3(128, 2), 512, 0, stream>>>(embed, Wih_f, b_f, Wih_b, b_b);
    prep_bpack<<<64, 256, 0, stream>>>(Whh_f, Whh_b);
    lstm_mfma <<<dim3(NN / SPB, 2), 256, 0, stream>>>(x, out);
}